// Round 10
// baseline (177.820 us; speedup 1.0000x reference)
//
#include <hip/hip_runtime.h>

#define NMENT 4096
#define GDIM  512
#define NPAD  160
#define NOUT  150

typedef _Float16 f16x8 __attribute__((ext_vector_type(8)));
typedef _Float16 f16x4 __attribute__((ext_vector_type(4)));
typedef float    f32x4 __attribute__((ext_vector_type(4)));
typedef float    f32x2 __attribute__((ext_vector_type(2)));

#if defined(__has_builtin)
#if __has_builtin(__builtin_amdgcn_cvt_pk_f32_fp8) && __has_builtin(__builtin_amdgcn_cvt_pk_fp8_f32)
#define FP8_HW 1
#endif
#endif

// ---------------- fp8 e4m3 helpers (HW cvt when available) ----------------
__device__ __forceinline__ float fp8_dec1f(unsigned b) {
    unsigned em = b & 0x7fu;
    unsigned bits = (em < 8u) ? 0u : (((b & 0x80u) << 24) | ((em + 960u) << 20));
    return __builtin_bit_cast(float, bits);
}
__device__ __forceinline__ unsigned fp8_enc1f(float x) {
    float c = fminf(fmaxf(x, -448.f), 448.f);
    unsigned u = __builtin_bit_cast(unsigned, c);
    unsigned s = (u >> 24) & 0x80u;
    unsigned mag = (u & 0x7fffffffu) + 0x80000u;
    int em = (int)(mag >> 20) - 960;
    if (em <= 0) return s;
    if (em > 0x7e) em = 0x7e;
    return s | (unsigned)em;
}
__device__ __forceinline__ f32x2 fp8_dec2_lo(unsigned v) {
#ifdef FP8_HW
    return __builtin_amdgcn_cvt_pk_f32_fp8((int)v, false);
#else
    f32x2 r; r[0] = fp8_dec1f(v & 0xffu); r[1] = fp8_dec1f((v >> 8) & 0xffu); return r;
#endif
}
__device__ __forceinline__ f32x2 fp8_dec2_hi(unsigned v) {
#ifdef FP8_HW
    return __builtin_amdgcn_cvt_pk_f32_fp8((int)v, true);
#else
    f32x2 r; r[0] = fp8_dec1f((v >> 16) & 0xffu); r[1] = fp8_dec1f(v >> 24); return r;
#endif
}
__device__ __forceinline__ unsigned fp8_enc1(float x) {
#ifdef FP8_HW
    return (unsigned)__builtin_amdgcn_cvt_pk_fp8_f32(x, x, 0, false) & 0xffu;
#else
    return fp8_enc1f(x);
#endif
}
__device__ __forceinline__ unsigned fp8_pack4(float a, float b, float c, float d) {
#ifdef FP8_HW
    int v = __builtin_amdgcn_cvt_pk_fp8_f32(a, b, 0, false);
    v = __builtin_amdgcn_cvt_pk_fp8_f32(c, d, v, true);
    return (unsigned)v;
#else
    return fp8_enc1f(a) | (fp8_enc1f(b) << 8) | (fp8_enc1f(c) << 16) | (fp8_enc1f(d) << 24);
#endif
}
// product of two fp8x8 chunks -> fp8x8
__device__ __forceinline__ uint2 fp8_mul8_fp8(uint2 a, uint2 b) {
    f32x2 a0 = fp8_dec2_lo(a.x), a1 = fp8_dec2_hi(a.x);
    f32x2 a2 = fp8_dec2_lo(a.y), a3 = fp8_dec2_hi(a.y);
    f32x2 b0 = fp8_dec2_lo(b.x), b1 = fp8_dec2_hi(b.x);
    f32x2 b2 = fp8_dec2_lo(b.y), b3 = fp8_dec2_hi(b.y);
    f32x2 p0 = a0 * b0, p1 = a1 * b1, p2 = a2 * b2, p3 = a3 * b3;
    uint2 r;
    r.x = fp8_pack4(p0[0], p0[1], p1[0], p1[1]);
    r.y = fp8_pack4(p2[0], p2[1], p3[0], p3[1]);
    return r;
}

// workspace layout (bytes)
#define G8_OFF    0u         // [4096][512] fp8        = 2097152
#define WABC_OFF  2097152u   // [30][16][512] fp8 frag = 245760 (Wa t0-9, Wb t10-19, Wc t20-29)
#define NODEI_OFF 2342912u   // [4096][160] fp8        = 655360
#define NODEJ_OFF 2998272u   // [4096][160] fp8        = 655360
#define PHI_OFF   3653632u   // [210][160] fp8         = 33600
#define B1P_OFF   3687232u   // [160] f32
#define W2P_OFF   3687872u   // [160] f32
// total ~3.52 MiB

// ---------------------------------------------------------------------------
// prep: g8 (blocks 0..1023), W1a/b/c -> Wabc8 fp8 fragment-major
// (1024..1119, 96 blocks of 16-k strips), Phi8 (1120..1251), b1/W2 (1252/1253)
// Fragment layout: addr = (tile*16+ks)*512 + (c16*4+quad)*8 + jj
//   holds W[n = (tile%10)*16+c16][k = ks*32+quad*8+jj]; tile = sec*10 + n/16.
// ---------------------------------------------------------------------------
__global__ void prep_kernel(const float* __restrict__ g_i,
                            const float* __restrict__ de,
                            const float* __restrict__ ge,
                            const float* __restrict__ se,
                            const float* __restrict__ W1,
                            const float* __restrict__ b1,
                            const float* __restrict__ W2,
                            unsigned char* __restrict__ g8,
                            unsigned char* __restrict__ Wabc8,
                            unsigned char* __restrict__ Phi8,
                            float* __restrict__ b1p,
                            float* __restrict__ W2p)
{
    __shared__ float tl[16 * 152];
    const int b = blockIdx.x, tid = threadIdx.x;

    if (b < 1024) {
        const float4* g4 = (const float4*)g_i;
        int i4 = b * 512 + tid * 2;
        float4 v0 = g4[i4], v1 = g4[i4 + 1];
        unsigned lo = fp8_pack4(v0.x, v0.y, v0.z, v0.w);
        unsigned hi = fp8_pack4(v1.x, v1.y, v1.z, v1.w);
        ((uint2*)g8)[b * 256 + tid] = make_uint2(lo, hi);
    } else if (b < 1120) {
        int b2 = b - 1024;            // 96 blocks
        int sec = b2 >> 5, strip = b2 & 31;   // 16 k-rows per strip
        int rbase = sec * 512 + strip * 16;
        for (int idx = tid; idx < 16 * 150; idx += 256) {
            int kk = idx / 150, col = idx - kk * 150;
            tl[kk * 152 + col] = W1[(rbase + kk) * 150 + col];
        }
        __syncthreads();
        for (int idx = tid; idx < 160 * 16; idx += 256) {
            int n = idx >> 4, k = idx & 15;
            float v = (n < 150) ? tl[k * 152 + n] : 0.0f;
            int tile = sec * 10 + (n >> 4), c16 = n & 15;
            int kg = strip * 16 + k;
            int ks = kg >> 5, quad = (kg >> 3) & 3, jj = kg & 7;
            Wabc8[(tile * 16 + ks) * 512 + (c16 * 4 + quad) * 8 + jj]
                = (unsigned char)fp8_enc1(v);
        }
    } else if (b < 1252) {
        int e = (b - 1120) * 256 + tid;
        if (e < 210 * 160) {
            int c = e / 160, n = e - c * 160;
            float acc = 0.0f;
            if (n < 150) {
                int bk = c / 21, rest = c - bk * 21, gi = rest / 3, sp = rest - gi * 3;
                #pragma unroll 4
                for (int d = 0; d < 20; ++d) {
                    acc += de[bk * 20 + d] * W1[(1536 + d) * 150 + n];
                    acc += ge[gi * 20 + d] * W1[(1556 + d) * 150 + n];
                    acc += se[sp * 20 + d] * W1[(1576 + d) * 150 + n];
                }
            }
            Phi8[e] = (unsigned char)fp8_enc1(acc);
        }
    } else if (b == 1252) {
        if (tid < 160) b1p[tid] = (tid < 150) ? b1[tid] : 0.0f;
    } else {
        if (tid < 160) W2p[tid] = (tid < 150) ? W2[tid] : 0.0f;
    }
}

// ---------------------------------------------------------------------------
// p1: per block 32 g8 rows -> LDS, all-fp8 MFMA vs fragment-major Wa8/Wb8.
// 20 n-tiles (10 NodeI + 10 NodeJ) / 4 waves, M=32. grid = 128 blocks.
// ---------------------------------------------------------------------------
__global__ __launch_bounds__(256, 2) void p1_node(
    const unsigned char* __restrict__ g8,
    const unsigned char* __restrict__ Wabc8,
    const float* __restrict__ b1p,
    unsigned char* __restrict__ NodeI8,
    unsigned char* __restrict__ NodeJ8)
{
    __shared__ __align__(16) unsigned char A8s[32 * 528];
    const int tid = threadIdx.x;
    const int lane = tid & 63;
    const int col = lane & 15, quad = lane >> 4;
    const int rowbase = blockIdx.x * 32;

    #pragma unroll
    for (int idx = tid; idx < 32 * 32; idx += 256) {
        int row = idx >> 5, o = (idx & 31) * 16;
        uint4 v = *(const uint4*)(g8 + (rowbase + row) * 512 + o);
        *(uint4*)&A8s[row * 528 + o] = v;
    }
    __syncthreads();

    const int wS = __builtin_amdgcn_readfirstlane(tid >> 6);
    const unsigned char* bbase = Wabc8 + (wS * 5 * 16) * 512 + (col * 4 + quad) * 8;

    f32x4 acc[2][5];
    #pragma unroll
    for (int mt = 0; mt < 2; ++mt)
        #pragma unroll
        for (int tt = 0; tt < 5; ++tt) acc[mt][tt] = f32x4{0.f, 0.f, 0.f, 0.f};

    #pragma unroll 4
    for (int ks = 0; ks < 16; ++ks) {
        long av[2];
        #pragma unroll
        for (int mt = 0; mt < 2; ++mt)
            av[mt] = *(const long*)&A8s[(mt * 16 + col) * 528 + ks * 32 + quad * 8];
        #pragma unroll
        for (int tt = 0; tt < 5; ++tt) {
            long bv = *(const long*)(bbase + (tt * 16 + ks) * 512);
            #pragma unroll
            for (int mt = 0; mt < 2; ++mt)
                acc[mt][tt] = __builtin_amdgcn_mfma_f32_16x16x32_fp8_fp8(
                    av[mt], bv, acc[mt][tt], 0, 0, 0);
        }
    }

    #pragma unroll
    for (int tt = 0; tt < 5; ++tt) {
        int tglob = wS * 5 + tt;
        bool isI = tglob < 10;
        int n = (isI ? tglob : tglob - 10) * 16 + col;
        unsigned char* outp = isI ? NodeI8 : NodeJ8;
        float bias = isI ? b1p[n] : 0.0f;
        #pragma unroll
        for (int mt = 0; mt < 2; ++mt)
            #pragma unroll
            for (int r = 0; r < 4; ++r) {
                int row = rowbase + mt * 16 + quad * 4 + r;
                outp[row * NPAD + n] = (unsigned char)fp8_enc1(acc[mt][tt][r] + bias);
            }
    }
}

// ---------------------------------------------------------------------------
// main R10: R8 K-split structure; launch bounds (256,6) (VGPR cap 80 >> 48
// measured need -> no spill; LDS 22.5KB x6 = 135KB -> 6 blocks/CU).
// Epilogue index computation + table base addresses hoisted above the CLDS
// write barrier so the NI/NJ/PH gathers issue immediately after it.
// ---------------------------------------------------------------------------
__global__ __launch_bounds__(256, 6) void pair_score_kernel(
    const unsigned char* __restrict__ g8,
    const unsigned char* __restrict__ Wc8,
    const unsigned char* __restrict__ NodeI8,
    const unsigned char* __restrict__ NodeJ8,
    const unsigned char* __restrict__ Phi8,
    const float* __restrict__ W2p,
    const float* __restrict__ msc,
    const float* __restrict__ b2,
    const int* __restrict__ mention_ids,
    const int* __restrict__ ant_ids,
    const int* __restrict__ dists,
    const int* __restrict__ genres,
    const int* __restrict__ speakers,
    const int* __restrict__ ant_counts,
    float* __restrict__ out)
{
    // union: A-half [64][272] fp8 (17408B) during GEMM; CLDS16 [64][168] f16
    // (21504B) after. 64*336 = 21504 bytes.
    __shared__ __align__(16) unsigned char smem[64 * 336];
    __shared__ int   m_lds[64], a_lds[64];
    __shared__ float sc[64];

    const int tid = threadIdx.x, s = blockIdx.x;
    const int lane = tid & 63;
    const int col = lane & 15, quad = lane >> 4;

    // --- phase 1: metadata ---
    if (tid < 64) {
        int p = s * 64 + tid;
        m_lds[tid] = mention_ids[p];
        a_lds[tid] = ant_ids[p];
    }
    __syncthreads();

    const int wS = __builtin_amdgcn_readfirstlane(tid >> 6);
    const int base = (wS < 2) ? wS * 3 : 6 + (wS - 2) * 2;
    const int cnt  = (wS < 2) ? 3 : 2;
    const int laneoff = (col * 4 + quad) * 8;
    const unsigned char* bbase = Wc8 + base * 16 * 512 + laneoff;

    f32x4 acc[4][3];
    #pragma unroll
    for (int mt = 0; mt < 4; ++mt)
        #pragma unroll
        for (int tt = 0; tt < 3; ++tt) acc[mt][tt] = f32x4{0.f, 0.f, 0.f, 0.f};

    // --- phases 2+3: two K-halves through one A buffer ---
    #pragma unroll
    for (int half = 0; half < 2; ++half) {
        // stage A-half: 64 rows x 256 B, row stride 272
        #pragma unroll
        for (int k = 0; k < 4; ++k) {
            int chunk = tid + k * 256;           // 0..1023
            int row = chunk >> 4, ko = (chunk & 15) * 16;
            const unsigned char* gi8 = g8 + m_lds[row] * 512 + half * 256 + ko;
            const unsigned char* gj8 = g8 + a_lds[row] * 512 + half * 256 + ko;
            uint4 gi = *(const uint4*)gi8;
            uint4 gj = *(const uint4*)gj8;
            uint2 lo = fp8_mul8_fp8(make_uint2(gi.x, gi.y), make_uint2(gj.x, gj.y));
            uint2 hi = fp8_mul8_fp8(make_uint2(gi.z, gi.w), make_uint2(gj.z, gj.w));
            *(uint4*)&smem[row * 272 + ko] = make_uint4(lo.x, lo.y, hi.x, hi.y);
        }
        __syncthreads();

        // GEMM on this half: ks = half*8 + ksl
        #pragma unroll
        for (int ksl = 0; ksl < 8; ++ksl) {
            long av[4];
            #pragma unroll
            for (int mt = 0; mt < 4; ++mt)
                av[mt] = *(const long*)&smem[(mt * 16 + col) * 272 + ksl * 32 + quad * 8];
            #pragma unroll
            for (int tt = 0; tt < 3; ++tt) {
                if (tt < cnt) {
                    long bv = *(const long*)(bbase + (tt * 16 + half * 8 + ksl) * 512);
                    #pragma unroll
                    for (int mt = 0; mt < 4; ++mt)
                        acc[mt][tt] = __builtin_amdgcn_mfma_f32_16x16x32_fp8_fp8(
                            av[mt], bv, acc[mt][tt], 0, 0, 0);
                }
            }
        }
        __syncthreads();   // half done: safe to overwrite A buffer / reuse as CLDS
    }

    // --- epilogue prefix (hoisted above the CLDS write): indices + bases ---
    const int pe = tid >> 2, q = tid & 3;
    const int pp = s * 64 + pe;
    const int me = m_lds[pe], ae = a_lds[pe];
    const int d = dists[pp];
    const int bk = (d>=1)+(d>=2)+(d>=3)+(d>=4)+(d>=8)+(d>=16)+(d>=32)+(d>=64);
    const int ce = (bk * 7 + genres[pp]) * 3 + speakers[pp];
    const uint2* NI = (const uint2*)(NodeI8 + me * NPAD + q * 40);
    const uint2* NJ = (const uint2*)(NodeJ8 + ae * NPAD + q * 40);
    const uint2* PH = (const uint2*)(Phi8 + ce * NPAD + q * 40);

    // --- phase 4: dump acc to CLDS16 [pair][col] f16, stride 168 ---
    _Float16* CLDS16 = (_Float16*)smem;
    #pragma unroll
    for (int tt = 0; tt < 3; ++tt) {
        if (tt < cnt) {
            #pragma unroll
            for (int mt = 0; mt < 4; ++mt)
                #pragma unroll
                for (int r = 0; r < 4; ++r)
                    CLDS16[(mt * 16 + quad * 4 + r) * 168 + (base + tt) * 16 + col]
                        = (_Float16)acc[mt][tt][r];
        }
    }
    __syncthreads();

    // --- phase 5: epilogue, thread = (pair pe, quarter q) ---
    const _Float16* crow = CLDS16 + pe * 168 + q * 40;
    const float* w2r = W2p + q * 40;

    float sum = 0.0f;
    #pragma unroll
    for (int i = 0; i < 5; ++i) {
        uint2 ni = NI[i], nj = NJ[i], ph = PH[i];
        f16x4 c0 = *(const f16x4*)(crow + i * 8);
        f16x4 c1 = *(const f16x4*)(crow + i * 8 + 4);
        float4 w0 = *(const float4*)(w2r + i * 8);
        float4 w1 = *(const float4*)(w2r + i * 8 + 4);
        f32x2 niA = fp8_dec2_lo(ni.x), niB = fp8_dec2_hi(ni.x);
        f32x2 niC = fp8_dec2_lo(ni.y), niD = fp8_dec2_hi(ni.y);
        f32x2 njA = fp8_dec2_lo(nj.x), njB = fp8_dec2_hi(nj.x);
        f32x2 njC = fp8_dec2_lo(nj.y), njD = fp8_dec2_hi(nj.y);
        f32x2 phA = fp8_dec2_lo(ph.x), phB = fp8_dec2_hi(ph.x);
        f32x2 phC = fp8_dec2_lo(ph.y), phD = fp8_dec2_hi(ph.y);
        sum += fmaxf((float)c0[0] + niA[0] + njA[0] + phA[0], 0.0f) * w0.x;
        sum += fmaxf((float)c0[1] + niA[1] + njA[1] + phA[1], 0.0f) * w0.y;
        sum += fmaxf((float)c0[2] + niB[0] + njB[0] + phB[0], 0.0f) * w0.z;
        sum += fmaxf((float)c0[3] + niB[1] + njB[1] + phB[1], 0.0f) * w0.w;
        sum += fmaxf((float)c1[0] + niC[0] + njC[0] + phC[0], 0.0f) * w1.x;
        sum += fmaxf((float)c1[1] + niC[1] + njC[1] + phC[1], 0.0f) * w1.y;
        sum += fmaxf((float)c1[2] + niD[0] + njD[0] + phD[0], 0.0f) * w1.z;
        sum += fmaxf((float)c1[3] + niD[1] + njD[1] + phD[1], 0.0f) * w1.w;
    }
    sum += __shfl_xor(sum, 1);
    sum += __shfl_xor(sum, 2);
    if (q == 0) sc[pe] = sum;
    __syncthreads();

    // --- phase 6: fused masked softmax + epsilon column + pad ---
    if (tid < 64) {
        int cnt2 = ant_counts[s];
        bool valid = tid < cnt2;
        float logit = valid
            ? (sc[tid] + msc[m_lds[tid]] + msc[a_lds[tid]] + b2[0])
            : -1e30f;
        float mx = logit;
        mx = fmaxf(mx, __shfl_xor(mx, 1));  mx = fmaxf(mx, __shfl_xor(mx, 2));
        mx = fmaxf(mx, __shfl_xor(mx, 4));  mx = fmaxf(mx, __shfl_xor(mx, 8));
        mx = fmaxf(mx, __shfl_xor(mx, 16)); mx = fmaxf(mx, __shfl_xor(mx, 32));
        mx = fmaxf(mx, 0.0f);
        float e = __expf(logit - mx);
        float ssum = e;
        ssum += __shfl_xor(ssum, 1);  ssum += __shfl_xor(ssum, 2);
        ssum += __shfl_xor(ssum, 4);  ssum += __shfl_xor(ssum, 8);
        ssum += __shfl_xor(ssum, 16); ssum += __shfl_xor(ssum, 32);
        float eps = __expf(-mx);
        ssum += eps;
        float* orow = out + s * 65;
        orow[tid] = valid ? (e / ssum) : 1000.0f;
        if (tid == 0) orow[64] = eps / ssum;
    }
}

// ---------------------------------------------------------------------------
extern "C" void kernel_launch(void* const* d_in, const int* in_sizes, int n_in,
                              void* d_out, int out_size, void* d_ws, size_t ws_size,
                              hipStream_t stream)
{
    const float* g_i = (const float*)d_in[0];
    const float* msc = (const float*)d_in[1];
    const float* de  = (const float*)d_in[2];
    const float* ge  = (const float*)d_in[3];
    const float* se  = (const float*)d_in[4];
    const float* W1  = (const float*)d_in[5];
    const float* b1  = (const float*)d_in[6];
    const float* W2  = (const float*)d_in[7];
    const float* b2  = (const float*)d_in[8];
    const int* mid  = (const int*)d_in[9];
    const int* aid  = (const int*)d_in[10];
    const int* dst  = (const int*)d_in[11];
    const int* gen  = (const int*)d_in[12];
    const int* spk  = (const int*)d_in[13];
    const int* cnts = (const int*)d_in[14];

    char* ws = (char*)d_ws;
    unsigned char* g8    = (unsigned char*)(ws + G8_OFF);
    unsigned char* Wabc8 = (unsigned char*)(ws + WABC_OFF);
    unsigned char* NodeI = (unsigned char*)(ws + NODEI_OFF);
    unsigned char* NodeJ = (unsigned char*)(ws + NODEJ_OFF);
    unsigned char* Phi8  = (unsigned char*)(ws + PHI_OFF);
    float*         b1p   = (float*)(ws + B1P_OFF);
    float*         W2p   = (float*)(ws + W2P_OFF);

    prep_kernel<<<dim3(1254), dim3(256), 0, stream>>>(
        g_i, de, ge, se, W1, b1, W2, g8, Wabc8, Phi8, b1p, W2p);

    p1_node<<<dim3(128), dim3(256), 0, stream>>>(
        g8, Wabc8, b1p, NodeI, NodeJ);

    pair_score_kernel<<<dim3(4096), dim3(256), 0, stream>>>(
        g8, Wabc8 + 20 * 16 * 512, NodeI, NodeJ, Phi8, W2p, msc, b2,
        mid, aid, dst, gen, spk, cnts, (float*)d_out);
}

// Round 11
// 160.936 us; speedup vs baseline: 1.1049x; 1.1049x over previous
//
#include <hip/hip_runtime.h>

#define NMENT 4096
#define GDIM  512
#define NPAD  160
#define NOUT  150

typedef _Float16 f16x8 __attribute__((ext_vector_type(8)));
typedef _Float16 f16x4 __attribute__((ext_vector_type(4)));
typedef float    f32x4 __attribute__((ext_vector_type(4)));
typedef float    f32x2 __attribute__((ext_vector_type(2)));

#if defined(__has_builtin)
#if __has_builtin(__builtin_amdgcn_cvt_pk_f32_fp8) && __has_builtin(__builtin_amdgcn_cvt_pk_fp8_f32)
#define FP8_HW 1
#endif
#endif

// ---------------- fp8 e4m3 helpers (HW cvt when available) ----------------
__device__ __forceinline__ float fp8_dec1f(unsigned b) {
    unsigned em = b & 0x7fu;
    unsigned bits = (em < 8u) ? 0u : (((b & 0x80u) << 24) | ((em + 960u) << 20));
    return __builtin_bit_cast(float, bits);
}
__device__ __forceinline__ unsigned fp8_enc1f(float x) {
    float c = fminf(fmaxf(x, -448.f), 448.f);
    unsigned u = __builtin_bit_cast(unsigned, c);
    unsigned s = (u >> 24) & 0x80u;
    unsigned mag = (u & 0x7fffffffu) + 0x80000u;
    int em = (int)(mag >> 20) - 960;
    if (em <= 0) return s;
    if (em > 0x7e) em = 0x7e;
    return s | (unsigned)em;
}
__device__ __forceinline__ f32x2 fp8_dec2_lo(unsigned v) {
#ifdef FP8_HW
    return __builtin_amdgcn_cvt_pk_f32_fp8((int)v, false);
#else
    f32x2 r; r[0] = fp8_dec1f(v & 0xffu); r[1] = fp8_dec1f((v >> 8) & 0xffu); return r;
#endif
}
__device__ __forceinline__ f32x2 fp8_dec2_hi(unsigned v) {
#ifdef FP8_HW
    return __builtin_amdgcn_cvt_pk_f32_fp8((int)v, true);
#else
    f32x2 r; r[0] = fp8_dec1f((v >> 16) & 0xffu); r[1] = fp8_dec1f(v >> 24); return r;
#endif
}
__device__ __forceinline__ unsigned fp8_enc1(float x) {
#ifdef FP8_HW
    return (unsigned)__builtin_amdgcn_cvt_pk_fp8_f32(x, x, 0, false) & 0xffu;
#else
    return fp8_enc1f(x);
#endif
}
__device__ __forceinline__ unsigned fp8_pack4(float a, float b, float c, float d) {
#ifdef FP8_HW
    int v = __builtin_amdgcn_cvt_pk_fp8_f32(a, b, 0, false);
    v = __builtin_amdgcn_cvt_pk_fp8_f32(c, d, v, true);
    return (unsigned)v;
#else
    return fp8_enc1f(a) | (fp8_enc1f(b) << 8) | (fp8_enc1f(c) << 16) | (fp8_enc1f(d) << 24);
#endif
}
// product of two fp8x8 chunks -> fp8x8
__device__ __forceinline__ uint2 fp8_mul8_fp8(uint2 a, uint2 b) {
    f32x2 a0 = fp8_dec2_lo(a.x), a1 = fp8_dec2_hi(a.x);
    f32x2 a2 = fp8_dec2_lo(a.y), a3 = fp8_dec2_hi(a.y);
    f32x2 b0 = fp8_dec2_lo(b.x), b1 = fp8_dec2_hi(b.x);
    f32x2 b2 = fp8_dec2_lo(b.y), b3 = fp8_dec2_hi(b.y);
    f32x2 p0 = a0 * b0, p1 = a1 * b1, p2 = a2 * b2, p3 = a3 * b3;
    uint2 r;
    r.x = fp8_pack4(p0[0], p0[1], p1[0], p1[1]);
    r.y = fp8_pack4(p2[0], p2[1], p3[0], p3[1]);
    return r;
}

// workspace layout (bytes)
#define G8_OFF    0u         // [4096][512] fp8        = 2097152
#define WABC_OFF  2097152u   // [30][16][512] fp8 frag = 245760 (Wa t0-9, Wb t10-19, Wc t20-29)
#define NODEI_OFF 2342912u   // [4096][160] fp8        = 655360
#define NODEJ_OFF 2998272u   // [4096][160] fp8        = 655360
#define PHI_OFF   3653632u   // [210][160] fp8         = 33600
#define B1P_OFF   3687232u   // [160] f32
#define W2P_OFF   3687872u   // [160] f32
// total ~3.52 MiB

// ---------------------------------------------------------------------------
// prep (small): W1a/b/c -> Wabc8 fp8 fragment-major (blocks 0..95),
// Phi8 (96..227), b1p (228), W2p (229). g8 conversion moved into p1_node.
// Fragment layout: addr = (tile*16+ks)*512 + (c16*4+quad)*8 + jj
// ---------------------------------------------------------------------------
__global__ void prep_kernel(const float* __restrict__ de,
                            const float* __restrict__ ge,
                            const float* __restrict__ se,
                            const float* __restrict__ W1,
                            const float* __restrict__ b1,
                            const float* __restrict__ W2,
                            unsigned char* __restrict__ Wabc8,
                            unsigned char* __restrict__ Phi8,
                            float* __restrict__ b1p,
                            float* __restrict__ W2p)
{
    __shared__ float tl[16 * 152];
    const int b = blockIdx.x, tid = threadIdx.x;

    if (b < 96) {
        int sec = b >> 5, strip = b & 31;   // 16 k-rows per strip
        int rbase = sec * 512 + strip * 16;
        for (int idx = tid; idx < 16 * 150; idx += 256) {
            int kk = idx / 150, col = idx - kk * 150;
            tl[kk * 152 + col] = W1[(rbase + kk) * 150 + col];
        }
        __syncthreads();
        for (int idx = tid; idx < 160 * 16; idx += 256) {
            int n = idx >> 4, k = idx & 15;
            float v = (n < 150) ? tl[k * 152 + n] : 0.0f;
            int tile = sec * 10 + (n >> 4), c16 = n & 15;
            int kg = strip * 16 + k;
            int ks = kg >> 5, quad = (kg >> 3) & 3, jj = kg & 7;
            Wabc8[(tile * 16 + ks) * 512 + (c16 * 4 + quad) * 8 + jj]
                = (unsigned char)fp8_enc1(v);
        }
    } else if (b < 228) {
        int e = (b - 96) * 256 + tid;
        if (e < 210 * 160) {
            int c = e / 160, n = e - c * 160;
            float acc = 0.0f;
            if (n < 150) {
                int bk = c / 21, rest = c - bk * 21, gi = rest / 3, sp = rest - gi * 3;
                #pragma unroll 4
                for (int d = 0; d < 20; ++d) {
                    acc += de[bk * 20 + d] * W1[(1536 + d) * 150 + n];
                    acc += ge[gi * 20 + d] * W1[(1556 + d) * 150 + n];
                    acc += se[sp * 20 + d] * W1[(1576 + d) * 150 + n];
                }
            }
            Phi8[e] = (unsigned char)fp8_enc1(acc);
        }
    } else if (b == 228) {
        if (tid < 160) b1p[tid] = (tid < 150) ? b1[tid] : 0.0f;
    } else {
        if (tid < 160) W2p[tid] = (tid < 150) ? W2[tid] : 0.0f;
    }
}

// ---------------------------------------------------------------------------
// p1 + g8 conversion: block b owns rows 32b..32b+31. Reads g_i (f32),
// converts to fp8, writes g8 (global) and stages LDS copy; then node GEMM
// vs fragment-major Wa8/Wb8 (20 n-tiles / 4 waves, M=32). grid = 128.
// ---------------------------------------------------------------------------
__global__ __launch_bounds__(256, 2) void p1_node(
    const float* __restrict__ g_i,
    const unsigned char* __restrict__ Wabc8,
    const float* __restrict__ b1p,
    unsigned char* __restrict__ g8,
    unsigned char* __restrict__ NodeI8,
    unsigned char* __restrict__ NodeJ8)
{
    __shared__ __align__(16) unsigned char A8s[32 * 528];
    const int tid = threadIdx.x;
    const int lane = tid & 63;
    const int col = lane & 15, quad = lane >> 4;
    const int rowbase = blockIdx.x * 32;

    // stage: convert 32 rows x 512 f32 -> fp8; write LDS + global g8
    #pragma unroll
    for (int idx = tid; idx < 32 * 64; idx += 256) {      // 8 iters, 8 elems each
        int row = idx >> 6, o = (idx & 63) * 8;
        const float4* src = (const float4*)(g_i + (rowbase + row) * 512 + o);
        float4 v0 = src[0], v1 = src[1];
        unsigned lo = fp8_pack4(v0.x, v0.y, v0.z, v0.w);
        unsigned hi = fp8_pack4(v1.x, v1.y, v1.z, v1.w);
        uint2 pk = make_uint2(lo, hi);
        *(uint2*)&A8s[row * 528 + o] = pk;
        *(uint2*)(g8 + (rowbase + row) * 512 + o) = pk;
    }
    __syncthreads();

    const int wS = __builtin_amdgcn_readfirstlane(tid >> 6);
    const unsigned char* bbase = Wabc8 + (wS * 5 * 16) * 512 + (col * 4 + quad) * 8;

    f32x4 acc[2][5];
    #pragma unroll
    for (int mt = 0; mt < 2; ++mt)
        #pragma unroll
        for (int tt = 0; tt < 5; ++tt) acc[mt][tt] = f32x4{0.f, 0.f, 0.f, 0.f};

    #pragma unroll 4
    for (int ks = 0; ks < 16; ++ks) {
        long av[2];
        #pragma unroll
        for (int mt = 0; mt < 2; ++mt)
            av[mt] = *(const long*)&A8s[(mt * 16 + col) * 528 + ks * 32 + quad * 8];
        #pragma unroll
        for (int tt = 0; tt < 5; ++tt) {
            long bv = *(const long*)(bbase + (tt * 16 + ks) * 512);
            #pragma unroll
            for (int mt = 0; mt < 2; ++mt)
                acc[mt][tt] = __builtin_amdgcn_mfma_f32_16x16x32_fp8_fp8(
                    av[mt], bv, acc[mt][tt], 0, 0, 0);
        }
    }

    #pragma unroll
    for (int tt = 0; tt < 5; ++tt) {
        int tglob = wS * 5 + tt;
        bool isI = tglob < 10;
        int n = (isI ? tglob : tglob - 10) * 16 + col;
        unsigned char* outp = isI ? NodeI8 : NodeJ8;
        float bias = isI ? b1p[n] : 0.0f;
        #pragma unroll
        for (int mt = 0; mt < 2; ++mt)
            #pragma unroll
            for (int r = 0; r < 4; ++r) {
                int row = rowbase + mt * 16 + quad * 4 + r;
                outp[row * NPAD + n] = (unsigned char)fp8_enc1(acc[mt][tt][r] + bias);
            }
    }
}

// ---------------------------------------------------------------------------
// main R11: R8 K-split structure at proven (256,5) (cap 102 — headroom for
// the hoisted epilogue prefix; R10's (256,6)=85 cap + hoist caused spill).
// ---------------------------------------------------------------------------
__global__ __launch_bounds__(256, 5) void pair_score_kernel(
    const unsigned char* __restrict__ g8,
    const unsigned char* __restrict__ Wc8,
    const unsigned char* __restrict__ NodeI8,
    const unsigned char* __restrict__ NodeJ8,
    const unsigned char* __restrict__ Phi8,
    const float* __restrict__ W2p,
    const float* __restrict__ msc,
    const float* __restrict__ b2,
    const int* __restrict__ mention_ids,
    const int* __restrict__ ant_ids,
    const int* __restrict__ dists,
    const int* __restrict__ genres,
    const int* __restrict__ speakers,
    const int* __restrict__ ant_counts,
    float* __restrict__ out)
{
    // union: A-half [64][272] fp8 (17408B) during GEMM; CLDS16 [64][168] f16
    // (21504B) after. 64*336 = 21504 bytes.
    __shared__ __align__(16) unsigned char smem[64 * 336];
    __shared__ int   m_lds[64], a_lds[64];
    __shared__ float sc[64];

    const int tid = threadIdx.x, s = blockIdx.x;
    const int lane = tid & 63;
    const int col = lane & 15, quad = lane >> 4;

    // --- phase 1: metadata ---
    if (tid < 64) {
        int p = s * 64 + tid;
        m_lds[tid] = mention_ids[p];
        a_lds[tid] = ant_ids[p];
    }
    __syncthreads();

    const int wS = __builtin_amdgcn_readfirstlane(tid >> 6);
    const int base = (wS < 2) ? wS * 3 : 6 + (wS - 2) * 2;
    const int cnt  = (wS < 2) ? 3 : 2;
    const int laneoff = (col * 4 + quad) * 8;
    const unsigned char* bbase = Wc8 + base * 16 * 512 + laneoff;

    f32x4 acc[4][3];
    #pragma unroll
    for (int mt = 0; mt < 4; ++mt)
        #pragma unroll
        for (int tt = 0; tt < 3; ++tt) acc[mt][tt] = f32x4{0.f, 0.f, 0.f, 0.f};

    // --- phases 2+3: two K-halves through one A buffer ---
    #pragma unroll
    for (int half = 0; half < 2; ++half) {
        // stage A-half: 64 rows x 256 B, row stride 272
        #pragma unroll
        for (int k = 0; k < 4; ++k) {
            int chunk = tid + k * 256;           // 0..1023
            int row = chunk >> 4, ko = (chunk & 15) * 16;
            const unsigned char* gi8 = g8 + m_lds[row] * 512 + half * 256 + ko;
            const unsigned char* gj8 = g8 + a_lds[row] * 512 + half * 256 + ko;
            uint4 gi = *(const uint4*)gi8;
            uint4 gj = *(const uint4*)gj8;
            uint2 lo = fp8_mul8_fp8(make_uint2(gi.x, gi.y), make_uint2(gj.x, gj.y));
            uint2 hi = fp8_mul8_fp8(make_uint2(gi.z, gi.w), make_uint2(gj.z, gj.w));
            *(uint4*)&smem[row * 272 + ko] = make_uint4(lo.x, lo.y, hi.x, hi.y);
        }
        __syncthreads();

        // GEMM on this half: ks = half*8 + ksl
        #pragma unroll
        for (int ksl = 0; ksl < 8; ++ksl) {
            long av[4];
            #pragma unroll
            for (int mt = 0; mt < 4; ++mt)
                av[mt] = *(const long*)&smem[(mt * 16 + col) * 272 + ksl * 32 + quad * 8];
            #pragma unroll
            for (int tt = 0; tt < 3; ++tt) {
                if (tt < cnt) {
                    long bv = *(const long*)(bbase + (tt * 16 + half * 8 + ksl) * 512);
                    #pragma unroll
                    for (int mt = 0; mt < 4; ++mt)
                        acc[mt][tt] = __builtin_amdgcn_mfma_f32_16x16x32_fp8_fp8(
                            av[mt], bv, acc[mt][tt], 0, 0, 0);
                }
            }
        }
        __syncthreads();   // half done: safe to overwrite A buffer / reuse as CLDS
    }

    // --- epilogue prefix (hoisted above the CLDS write): indices + bases ---
    const int pe = tid >> 2, q = tid & 3;
    const int pp = s * 64 + pe;
    const int me = m_lds[pe], ae = a_lds[pe];
    const int d = dists[pp];
    const int bk = (d>=1)+(d>=2)+(d>=3)+(d>=4)+(d>=8)+(d>=16)+(d>=32)+(d>=64);
    const int ce = (bk * 7 + genres[pp]) * 3 + speakers[pp];
    const uint2* NI = (const uint2*)(NodeI8 + me * NPAD + q * 40);
    const uint2* NJ = (const uint2*)(NodeJ8 + ae * NPAD + q * 40);
    const uint2* PH = (const uint2*)(Phi8 + ce * NPAD + q * 40);

    // --- phase 4: dump acc to CLDS16 [pair][col] f16, stride 168 ---
    _Float16* CLDS16 = (_Float16*)smem;
    #pragma unroll
    for (int tt = 0; tt < 3; ++tt) {
        if (tt < cnt) {
            #pragma unroll
            for (int mt = 0; mt < 4; ++mt)
                #pragma unroll
                for (int r = 0; r < 4; ++r)
                    CLDS16[(mt * 16 + quad * 4 + r) * 168 + (base + tt) * 16 + col]
                        = (_Float16)acc[mt][tt][r];
        }
    }
    __syncthreads();

    // --- phase 5: epilogue, thread = (pair pe, quarter q) ---
    const _Float16* crow = CLDS16 + pe * 168 + q * 40;
    const float* w2r = W2p + q * 40;

    float sum = 0.0f;
    #pragma unroll
    for (int i = 0; i < 5; ++i) {
        uint2 ni = NI[i], nj = NJ[i], ph = PH[i];
        f16x4 c0 = *(const f16x4*)(crow + i * 8);
        f16x4 c1 = *(const f16x4*)(crow + i * 8 + 4);
        float4 w0 = *(const float4*)(w2r + i * 8);
        float4 w1 = *(const float4*)(w2r + i * 8 + 4);
        f32x2 niA = fp8_dec2_lo(ni.x), niB = fp8_dec2_hi(ni.x);
        f32x2 niC = fp8_dec2_lo(ni.y), niD = fp8_dec2_hi(ni.y);
        f32x2 njA = fp8_dec2_lo(nj.x), njB = fp8_dec2_hi(nj.x);
        f32x2 njC = fp8_dec2_lo(nj.y), njD = fp8_dec2_hi(nj.y);
        f32x2 phA = fp8_dec2_lo(ph.x), phB = fp8_dec2_hi(ph.x);
        f32x2 phC = fp8_dec2_lo(ph.y), phD = fp8_dec2_hi(ph.y);
        sum += fmaxf((float)c0[0] + niA[0] + njA[0] + phA[0], 0.0f) * w0.x;
        sum += fmaxf((float)c0[1] + niA[1] + njA[1] + phA[1], 0.0f) * w0.y;
        sum += fmaxf((float)c0[2] + niB[0] + njB[0] + phB[0], 0.0f) * w0.z;
        sum += fmaxf((float)c0[3] + niB[1] + njB[1] + phB[1], 0.0f) * w0.w;
        sum += fmaxf((float)c1[0] + niC[0] + njC[0] + phC[0], 0.0f) * w1.x;
        sum += fmaxf((float)c1[1] + niC[1] + njC[1] + phC[1], 0.0f) * w1.y;
        sum += fmaxf((float)c1[2] + niD[0] + njD[0] + phD[0], 0.0f) * w1.z;
        sum += fmaxf((float)c1[3] + niD[1] + njD[1] + phD[1], 0.0f) * w1.w;
    }
    sum += __shfl_xor(sum, 1);
    sum += __shfl_xor(sum, 2);
    if (q == 0) sc[pe] = sum;
    __syncthreads();

    // --- phase 6: fused masked softmax + epsilon column + pad ---
    if (tid < 64) {
        int cnt2 = ant_counts[s];
        bool valid = tid < cnt2;
        float logit = valid
            ? (sc[tid] + msc[m_lds[tid]] + msc[a_lds[tid]] + b2[0])
            : -1e30f;
        float mx = logit;
        mx = fmaxf(mx, __shfl_xor(mx, 1));  mx = fmaxf(mx, __shfl_xor(mx, 2));
        mx = fmaxf(mx, __shfl_xor(mx, 4));  mx = fmaxf(mx, __shfl_xor(mx, 8));
        mx = fmaxf(mx, __shfl_xor(mx, 16)); mx = fmaxf(mx, __shfl_xor(mx, 32));
        mx = fmaxf(mx, 0.0f);
        float e = __expf(logit - mx);
        float ssum = e;
        ssum += __shfl_xor(ssum, 1);  ssum += __shfl_xor(ssum, 2);
        ssum += __shfl_xor(ssum, 4);  ssum += __shfl_xor(ssum, 8);
        ssum += __shfl_xor(ssum, 16); ssum += __shfl_xor(ssum, 32);
        float eps = __expf(-mx);
        ssum += eps;
        float* orow = out + s * 65;
        orow[tid] = valid ? (e / ssum) : 1000.0f;
        if (tid == 0) orow[64] = eps / ssum;
    }
}

// ---------------------------------------------------------------------------
extern "C" void kernel_launch(void* const* d_in, const int* in_sizes, int n_in,
                              void* d_out, int out_size, void* d_ws, size_t ws_size,
                              hipStream_t stream)
{
    const float* g_i = (const float*)d_in[0];
    const float* msc = (const float*)d_in[1];
    const float* de  = (const float*)d_in[2];
    const float* ge  = (const float*)d_in[3];
    const float* se  = (const float*)d_in[4];
    const float* W1  = (const float*)d_in[5];
    const float* b1  = (const float*)d_in[6];
    const float* W2  = (const float*)d_in[7];
    const float* b2  = (const float*)d_in[8];
    const int* mid  = (const int*)d_in[9];
    const int* aid  = (const int*)d_in[10];
    const int* dst  = (const int*)d_in[11];
    const int* gen  = (const int*)d_in[12];
    const int* spk  = (const int*)d_in[13];
    const int* cnts = (const int*)d_in[14];

    char* ws = (char*)d_ws;
    unsigned char* g8    = (unsigned char*)(ws + G8_OFF);
    unsigned char* Wabc8 = (unsigned char*)(ws + WABC_OFF);
    unsigned char* NodeI = (unsigned char*)(ws + NODEI_OFF);
    unsigned char* NodeJ = (unsigned char*)(ws + NODEJ_OFF);
    unsigned char* Phi8  = (unsigned char*)(ws + PHI_OFF);
    float*         b1p   = (float*)(ws + B1P_OFF);
    float*         W2p   = (float*)(ws + W2P_OFF);

    prep_kernel<<<dim3(230), dim3(256), 0, stream>>>(
        de, ge, se, W1, b1, W2, Wabc8, Phi8, b1p, W2p);

    p1_node<<<dim3(128), dim3(256), 0, stream>>>(
        g_i, Wabc8, b1p, g8, NodeI, NodeJ);

    pair_score_kernel<<<dim3(4096), dim3(256), 0, stream>>>(
        g8, Wabc8 + 20 * 16 * 512, NodeI, NodeJ, Phi8, W2p, msc, b2,
        mid, aid, dst, gen, spk, cnts, (float*)d_out);
}